// Round 1
// baseline (478.395 us; speedup 1.0000x reference)
//
#include <hip/hip_runtime.h>

// CostVolume1D: out[n,i,h,w] = (1/C) * sum_c f1[n,c,h,w] * f2pad[n,c,h,w+i-4]
// N=4, C=128, H=192, W=640, D=4 -> 9 shifts.
//
// Memory-bound: 503 MB read + 17.7 MB write => ~83 us floor @6.3 TB/s.
// LDS-free design: each thread owns an aligned float4 of outputs (w..w+3) and
// loads f2[w-4..w+7] as 3 aligned float4s. The +-4 halo loads overlap the
// neighboring lanes' loads in the same wave -> L1 hits; HBM sees f2 ~once.
// No barriers -> waves pipeline the channel loop independently; depth-2
// prefetch keeps 8 loads (8 KB) in flight per wave, ~56 KB/CU >> the ~9 KB
// needed to saturate this CU's HBM share (Little's law).
//
// Zero-padding at row edges is handled at float4 granularity: edge threads
// clamp the halo address in-bounds (loading garbage), and the affected
// outputs -- exactly those whose f2 column index is OOB, which is a
// channel-invariant property, so their true sum is 0 -- are zeroed at store.

constexpr int DD = 4;
constexpr int NS = 2 * DD + 1;          // 9
constexpr int N_ = 4, C_ = 128, H_ = 192, W_ = 640;
constexpr int HW = H_ * W_;             // 122880

__device__ __forceinline__ float4 ld4(const float* p) {
    return *reinterpret_cast<const float4*>(p);
}

__global__ __launch_bounds__(160)
void cost_volume_kernel(const float* __restrict__ f1,
                        const float* __restrict__ f2,
                        float* __restrict__ out)
{
    const int t   = threadIdx.x;        // 0..159, owns w = 4t..4t+3
    const int row = blockIdx.x;         // n*H + h
    const int n   = row / H_;
    const int h   = row - n * H_;
    const int w   = 4 * t;

    const size_t base = (size_t)n * C_ * HW + (size_t)h * W_ + w;
    const float* pa = f1 + base;
    const float* p1 = f2 + base;
    // halo pointers, clamped in-bounds at row edges (t==0 left, t==159 right)
    const float* p0 = p1 + (w >= 4 ? -4 : 0);
    const float* p2 = p1 + (w + 7 < W_ ? 4 : 0);

    float acc[NS][4];
#pragma unroll
    for (int i = 0; i < NS; ++i)
#pragma unroll
        for (int j = 0; j < 4; ++j) acc[i][j] = 0.f;

    // v[k] = f2row[w - 4 + k], k = 0..11; shift i, lane-sub j uses v[i+j]
#define FMA_STEP(A, U, V, X)                                              \
    do {                                                                  \
        float vv[12];                                                     \
        *(float4*)&vv[0] = (U);                                           \
        *(float4*)&vv[4] = (V);                                           \
        *(float4*)&vv[8] = (X);                                           \
        const float* ap = (const float*)&(A);                             \
        _Pragma("unroll")                                                 \
        for (int i = 0; i < NS; ++i) {                                    \
            _Pragma("unroll")                                             \
            for (int j = 0; j < 4; ++j)                                   \
                acc[i][j] = fmaf(ap[j], vv[i + j], acc[i][j]);            \
        }                                                                 \
    } while (0)

    // depth-2 software pipeline: channels c and c+1 staged in registers,
    // prefetch c+2/c+3 while computing.
    float4 a0 = ld4(pa),      u0 = ld4(p0),      v0 = ld4(p1),      x0 = ld4(p2);
    float4 a1 = ld4(pa + HW), u1 = ld4(p0 + HW), v1 = ld4(p1 + HW), x1 = ld4(p2 + HW);
    pa += 2 * HW; p0 += 2 * HW; p1 += 2 * HW; p2 += 2 * HW;

    for (int c = 0; c < C_ - 2; c += 2) {
        float4 ta = ld4(pa), tu = ld4(p0), tv = ld4(p1), tx = ld4(p2);
        FMA_STEP(a0, u0, v0, x0);
        a0 = ta; u0 = tu; v0 = tv; x0 = tx;
        float4 sa = ld4(pa + HW), su = ld4(p0 + HW), sv = ld4(p1 + HW), sx = ld4(p2 + HW);
        FMA_STEP(a1, u1, v1, x1);
        a1 = sa; u1 = su; v1 = sv; x1 = sx;
        pa += 2 * HW; p0 += 2 * HW; p1 += 2 * HW; p2 += 2 * HW;
    }
    FMA_STEP(a0, u0, v0, x0);   // channel 126
    FMA_STEP(a1, u1, v1, x1);   // channel 127

#undef FMA_STEP

    constexpr float scale = 1.0f / (float)C_;
    float* op = out + (size_t)n * NS * HW + (size_t)h * W_ + w;
#pragma unroll
    for (int i = 0; i < NS; ++i) {
        float4 o;
        float* oo = (float*)&o;
#pragma unroll
        for (int j = 0; j < 4; ++j) {
            const int idx = w + i + j - DD;   // f2 column this product used
            oo[j] = (idx >= 0 && idx < W_) ? acc[i][j] * scale : 0.f;
        }
        *reinterpret_cast<float4*>(op + (size_t)i * HW) = o;
    }
}

extern "C" void kernel_launch(void* const* d_in, const int* in_sizes, int n_in,
                              void* d_out, int out_size, void* d_ws, size_t ws_size,
                              hipStream_t stream) {
    const float* f1 = (const float*)d_in[0];
    const float* f2 = (const float*)d_in[1];
    float* out = (float*)d_out;
    dim3 grid(N_ * H_);   // 768 blocks = one per (n,h) row; exactly 3/CU
    dim3 block(160);      // one row of 640 floats = 160 lanes x float4
    cost_volume_kernel<<<grid, block, 0, stream>>>(f1, f2, out);
}